// Round 8
// baseline (3996.021 us; speedup 1.0000x reference)
//
#include <hip/hip_runtime.h>

// ---------------------------------------------------------------------------
// Equilibrium-prop fixed-point net, MI355X — R8.
//   u1' = clip(0.5*(u1 + xW0 + u2@W1^T))
//   u2' = clip(0.5*(u2 + u1@W1 + u3@W2^T + b1))
//   u3' = clip(0.5*(u3 + u2@W2 + u4@W3^T + b2))
//   u4' = clip(0.5*(u4 + u3@W3 + b3)) | clip(0.5*(u3@W3+b3+t)) clamped
// R8 = R2 structure with SCHEDULE-INDEPENDENT staging:
//   - all staging loads issue, then ONE s_waitcnt vmcnt(0) + sched_barrier,
//     then unpack to LDS (hand-counted vmcnt(N) retired: it silently breaks
//     when the compiler hoists unrelated global loads into the window —
//     root cause of R6/R7 corruption; R2 passed only by schedule luck);
//   - u4 staging swizzle fixed to (row4&7)<<4 to match the read side
//     (R2 rows 8-15 read never-written LDS for the u4->u3 term);
//   - ILP: split accumulator chains (hh | hl+lh), doU4 tile first;
//   - R2's full 16-WG barrier verbatim (system-scope relaxed + poll).
// ---------------------------------------------------------------------------

typedef float  f32x4 __attribute__((ext_vector_type(4)));
typedef short  s16x8 __attribute__((ext_vector_type(8)));
typedef short  s16x4 __attribute__((ext_vector_type(4)));
typedef unsigned int uint;
typedef uint   u32x4 __attribute__((ext_vector_type(4)));

#define MFMA_BF16 __builtin_amdgcn_mfma_f32_16x16x32_bf16

#define NFREE   500
#define NCLAMP  8
#define NITER   (NFREE + NCLAMP)
#define ROWLEN  1568                   // [u1:512 | u2:512 | u3:512 | u4:32]
#define NSAMP   256
#define ROWTOT  (NSAMP * ROWLEN)

// packed-B element offsets (each block = 512 elems = one (ctile,kstep) frag)
#define B1_OFF   0                     // W1^T   (u1' <- u2), 32ct x 16ks
#define B2A_OFF  262144                // W1     (u2' <- u1)
#define B2B_OFF  524288                // W2^T   (u2' <- u3)
#define B3A_OFF  786432                // W2     (u3' <- u2)
#define B3B_OFF  1048576               // W3^T   (u3' <- u4), 32ct x 1ks
#define B4_OFF   1064960               // W3     (u4' <- u3), 1ct x 16ks
#define BTOT     1081344

// workspace layout (bytes)
#define WS_UHL   0                                   // 2 bufs x ROWTOT u32
#define WS_XW0   (WS_UHL + 2*ROWTOT*4)               // x@W0+b0, [256][512] f32
#define WS_BIAS  (WS_XW0 + NSAMP*512*4)              // [1568] f32
#define WS_CNT   (WS_BIAS + 6400)                    // 16 padded counters
#define WS_BH    (WS_CNT + 1024)
#define WS_BL    (WS_BH + BTOT*2)
#define WS_END   (WS_BL + BTOT*2)                    // ~8.07 MB

__device__ __forceinline__ short f2bf(float f){      // RNE f32->bf16
  unsigned u = __float_as_uint(f);
  unsigned r = (u + 0x7FFFu + ((u >> 16) & 1u)) >> 16;
  return (short)r;
}
__device__ __forceinline__ float bf2f(short s){
  return __uint_as_float(((unsigned)(unsigned short)s) << 16);
}
__device__ __forceinline__ uint packbf(float v){
  short h = f2bf(v);
  short l = f2bf(v - bf2f(h));
  return (uint)(unsigned short)h | ((uint)(unsigned short)l << 16);
}

// system-scope (LLC-coherent) accesses — no cache fences needed anywhere
#define SYSLD(dst, addr) \
  asm volatile("global_load_dwordx4 %0, %1, off sc0 sc1" : "=v"(dst) : "v"(addr) : "memory")
__device__ __forceinline__ void store_sys(uint* p, uint v){
  asm volatile("global_store_dword %0, %1, off sc0 sc1" :: "v"(p), "v"(v) : "memory");
}
// wait for ALL outstanding vmem — correct regardless of compiler-inserted ops
#define WAITALL() do { \
  asm volatile("s_waitcnt vmcnt(0)" ::: "memory"); \
  __builtin_amdgcn_sched_barrier(0); } while(0)
// unpack hi/lo + swizzled LDS write (hi at OFF, lo at OFF+32768)
#define UNPK(X, OFF) do { \
  s16x4 h_ = (s16x4){ (short)((X)[0] & 0xffff), (short)((X)[1] & 0xffff), \
                      (short)((X)[2] & 0xffff), (short)((X)[3] & 0xffff) }; \
  s16x4 l_ = (s16x4){ (short)((X)[0] >> 16), (short)((X)[1] >> 16), \
                      (short)((X)[2] >> 16), (short)((X)[3] >> 16) }; \
  *(s16x4*)(L + (OFF)) = h_; *(s16x4*)(L + 32768 + (OFF)) = l_; } while(0)

#define BARRIER(ITV) do { \
  asm volatile("s_waitcnt vmcnt(0)" ::: "memory"); \
  __syncthreads(); \
  if (tid == 0){ \
    __hip_atomic_fetch_add(cg, 1u, __ATOMIC_RELAXED, __HIP_MEMORY_SCOPE_SYSTEM); \
    const unsigned tgt_ = 16u * (unsigned)((ITV) + 1); \
    while (__hip_atomic_load(cg, __ATOMIC_RELAXED, __HIP_MEMORY_SCOPE_SYSTEM) < tgt_){ \
      __builtin_amdgcn_s_sleep(1); \
    } \
  } \
  __syncthreads(); } while(0)

// -------------------------- init: packed state, bias, counters --------------
__global__ void initK(const float* __restrict__ u1, const float* __restrict__ u2,
                      const float* __restrict__ u3, const float* __restrict__ u4,
                      const float* __restrict__ b1, const float* __restrict__ b2,
                      uint* __restrict__ uhl, float* __restrict__ bias,
                      uint* __restrict__ cnt){
  const int b = blockIdx.x, tid = threadIdx.x;
  for (int col = tid; col < ROWLEN; col += 256){
    float v;
    if      (col < 512)  v = (col < 500)        ? u1[b*500 + col]        : 0.f;
    else if (col < 1024) v = ((col-512) < 500)  ? u2[b*500 + col - 512]  : 0.f;
    else if (col < 1536) v = ((col-1024) < 500) ? u3[b*500 + col - 1024] : 0.f;
    else                 v = ((col-1536) < 10)  ? u4[b*10 + col - 1536]  : 0.f;
    uhl[b*ROWLEN + col] = packbf(v);
    if (b == 0){
      float bv = 0.f;
      if      (col >= 512  && col < 1024){ int i = col-512;  if (i < 500) bv = b1[i]; }
      else if (col >= 1024 && col < 1536){ int i = col-1024; if (i < 500) bv = b2[i]; }
      bias[col] = bv;
    }
  }
  if (b == 0) cnt[tid] = 0;
}

// -------------------------- xW0p = x @ W0 + b0 (fp32) -----------------------
__global__ void xw0K(const float* __restrict__ x, const float* __restrict__ W0,
                     const float* __restrict__ b0, float* __restrict__ xw0p){
  __shared__ float xs[784];
  const int b = blockIdx.x, tid = threadIdx.x;    // 512 threads
  for (int j = tid; j < 784; j += 512) xs[j] = x[b*784 + j];
  __syncthreads();
  float a = 0.f;
  if (tid < 500){
    a = b0[tid];
    #pragma unroll 4
    for (int j = 0; j < 784; ++j) a = fmaf(xs[j], W0[j*500 + tid], a);
  }
  xw0p[b*512 + tid] = (tid < 500) ? a : 0.f;
}

// ------------------- pack weights into MFMA B-fragment layout ---------------
__global__ void packK(const float* __restrict__ W1, const float* __restrict__ W2,
                      const float* __restrict__ W3, short* __restrict__ Bh,
                      short* __restrict__ Bl){
  const int bid = blockIdx.x, ln = threadIdx.x;   // 64 threads
  int m, base, nks, poff;
  if      (bid < 512) { m=0; base=0;    nks=16; poff=B1_OFF;  }
  else if (bid < 1024){ m=1; base=512;  nks=16; poff=B2A_OFF; }
  else if (bid < 1536){ m=2; base=1024; nks=16; poff=B2B_OFF; }
  else if (bid < 2048){ m=3; base=1536; nks=16; poff=B3A_OFF; }
  else if (bid < 2080){ m=4; base=2048; nks=1;  poff=B3B_OFF; }
  else                { m=5; base=2080; nks=16; poff=B4_OFF;  }
  const int local = bid - base, ct = local / nks, ks = local % nks;
  short hv[8], lv[8];
  #pragma unroll
  for (int j = 0; j < 8; ++j){
    const int k = ks*32 + (ln>>4)*8 + j;
    const int c = ct*16 + (ln & 15);
    float v = 0.f;
    if      (m==0){ if (k<500 && c<500) v = W1[c*500 + k]; }   // W1^T
    else if (m==1){ if (k<500 && c<500) v = W1[k*500 + c]; }   // W1
    else if (m==2){ if (k<500 && c<500) v = W2[c*500 + k]; }   // W2^T
    else if (m==3){ if (k<500 && c<500) v = W2[k*500 + c]; }   // W2
    else if (m==4){ if (k<10  && c<500) v = W3[c*10  + k]; }   // W3^T
    else          { if (k<500 && c<10 ) v = W3[k*10  + c]; }   // W3
    short h = f2bf(v); hv[j] = h; lv[j] = f2bf(v - bf2f(h));
  }
  const int o = poff + (ct*nks + ks)*512 + ln*8;
  #pragma unroll
  for (int j = 0; j < 8; ++j){ Bh[o+j] = hv[j]; Bl[o+j] = lv[j]; }
}

// ------------------------------- main loop ----------------------------------
// 256 WGs x 256 thr, 1 WG/CU. rg = bid&15 (16 samples), tp = bid>>4:
//   tp 0-7 : u2 tiles (K=1024, 32 ksteps). tp 8-11: u1. tp 12-15: u3.
// u4'-tile: tp==0, wave 0 (A=u3 from LDS, B4 streamed from L2).
__global__ void __launch_bounds__(256, 1) mainK(
    const short* __restrict__ Bh, const short* __restrict__ Bl,
    uint* __restrict__ uhl, const float* __restrict__ xw0p,
    const float* __restrict__ bias,
    const float* __restrict__ u1in, const float* __restrict__ u2in,
    const float* __restrict__ u3in, const float* __restrict__ u4in,
    const float* __restrict__ tin, const float* __restrict__ b3,
    float* __restrict__ dout, uint* __restrict__ cnt)
{
  __shared__ short ldss[32768];                 // 64 KiB: hi [0,32K), lo [32K,64K)
  char* L = (char*)ldss;
  const int bid = blockIdx.x;
  const int rg  = bid & 15;
  const int tp  = bid >> 4;
  const int tid = threadIdx.x;
  const int wv  = tid >> 6, ln = tid & 63;
  const int lrow = ln & 15, lkg = ln >> 4;
  const int rowbase = rg * 16;
  const int sg16 = tid >> 4, l16 = tid & 15;
  // A-frag LDS base: row*2048 + (k-group*16 ^ swizzle); ks*64 XORs in later
  const int abase = lrow*2048 + ((lkg*16) ^ ((lrow & 7) << 4));
  uint* cg = cnt + rg*16;

  if (tp < 8){
    // =============================== u2 path ===============================
    s16x8 bh[32], bl[32];                       // 256 VGPRs, live whole kernel
    const int ctg = tp*4 + wv;
    #pragma unroll
    for (int ks = 0; ks < 32; ++ks){
      const int of = (ks < 16 ? B2A_OFF + (ctg*16 + ks)*512
                              : B2B_OFF + (ctg*16 + ks - 16)*512) + ln*8;
      bh[ks] = *(const s16x8*)(Bh + of);
      bl[ks] = *(const s16x8*)(Bl + of);
    }
    const int i0 = tp*64 + wv*16 + lrow;        // col within u2 segment
    const int colg = 512 + i0;
    const float biasv = bias[colg];
    f32x4 uold, uold4;
    #pragma unroll
    for (int r = 0; r < 4; ++r){
      const int b = rowbase + lkg*4 + r;
      uold[r]  = (i0 < 500)   ? u2in[b*500 + i0]  : 0.f;
      uold4[r] = (lrow < 10)  ? u4in[b*10 + lrow] : 0.f;
    }
    const int rA = sg16 >> 1, half = sg16 & 1;
    const bool doU4 = (tp == 0 && wv == 0);

    for (int it = 0; it < NITER; ++it){
      const uint* uhlB = uhl + (size_t)(it & 1)*ROWTOT;
      uint*       uhlN = uhl + (size_t)((it & 1) ^ 1)*ROWTOT;
      const int snap = (it == NFREE-1) ? 0 : ((it == NITER-1) ? 386560 : -1);
      { // ---- stage A = u1 (half0) + u3 (half1), rows rA and rA+8 ----
        const uint* sA = uhlB + (size_t)(rowbase + rA)*ROWLEN + half*1024 + l16*4;
        const uint* sB = sA + 8*ROWLEN;
        u32x4 a0,a1,a2,a3,a4,a5,a6,a7,c0,c1,c2,c3,c4,c5,c6,c7;
        SYSLD(a0, sA+0);   SYSLD(a1, sA+64);  SYSLD(a2, sA+128); SYSLD(a3, sA+192);
        SYSLD(a4, sA+256); SYSLD(a5, sA+320); SYSLD(a6, sA+384); SYSLD(a7, sA+448);
        SYSLD(c0, sB+0);   SYSLD(c1, sB+64);  SYSLD(c2, sB+128); SYSLD(c3, sB+192);
        SYSLD(c4, sB+256); SYSLD(c5, sB+320); SYSLD(c6, sB+384); SYSLD(c7, sB+448);
        WAITALL();
        const int obA = rA*2048 + ((half*1024 + l16*8) ^ ((rA & 7) << 4));
        const int obB = obA + 16384;            // row+8: same swizzle bits
        UNPK(a0, obA+0);   UNPK(a1, obA+128); UNPK(a2, obA+256); UNPK(a3, obA+384);
        UNPK(a4, obA+512); UNPK(a5, obA+640); UNPK(a6, obA+768); UNPK(a7, obA+896);
        UNPK(c0, obB+0);   UNPK(c1, obB+128); UNPK(c2, obB+256); UNPK(c3, obB+384);
        UNPK(c4, obB+512); UNPK(c5, obB+640); UNPK(c6, obB+768); UNPK(c7, obB+896);
      }
      __syncthreads();
      // ---- doU4 tile FIRST (B4 loads issue early, drain under main) ----
      f32x4 h4 = {0.f,0.f,0.f,0.f}, x4 = {0.f,0.f,0.f,0.f};
      if (doU4){
        #pragma unroll
        for (int ks = 0; ks < 16; ++ks){
          const int off = (abase + 1024) ^ (ks*64);   // u3 half of panel
          s16x8 aH = *(const s16x8*)(L + off);
          s16x8 aL = *(const s16x8*)(L + 32768 + off);
          const int of4 = B4_OFF + ks*512 + ln*8;
          s16x8 b4h = *(const s16x8*)(Bh + of4);
          s16x8 b4l = *(const s16x8*)(Bl + of4);
          h4 = MFMA_BF16(aH, b4h, h4, 0, 0, 0);
          x4 = MFMA_BF16(aH, b4l, x4, 0, 0, 0);
          x4 = MFMA_BF16(aL, b4h, x4, 0, 0, 0);
        }
      }
      // ---- main: two independent chains (hh) and (hl+lh) ----
      f32x4 acch = {0.f,0.f,0.f,0.f}, accx = {0.f,0.f,0.f,0.f};
      #pragma unroll
      for (int ks = 0; ks < 32; ++ks){
        const int off = abase ^ (ks*64);
        s16x8 aH = *(const s16x8*)(L + off);
        s16x8 aL = *(const s16x8*)(L + 32768 + off);
        acch = MFMA_BF16(aH, bh[ks], acch, 0, 0, 0);
        accx = MFMA_BF16(aH, bl[ks], accx, 0, 0, 0);
        accx = MFMA_BF16(aL, bh[ks], accx, 0, 0, 0);
      }
      // ---- epilogue: u2' ----
      #pragma unroll
      for (int r = 0; r < 4; ++r){
        const int b = rowbase + lkg*4 + r;
        const float y = acch[r] + accx[r] + biasv;
        float v = 0.5f*(uold[r] + y);
        v = fminf(fmaxf(v, 0.f), 1.f);
        if (i0 >= 500) v = 0.f;
        uold[r] = v;
        store_sys(uhlN + (size_t)b*ROWLEN + colg, packbf(v));
        if (snap >= 0 && i0 < 500) dout[snap + 128000 + b*500 + i0] = v;
      }
      if (doU4){
        const bool clamped = (it >= NFREE);
        #pragma unroll
        for (int r = 0; r < 4; ++r){
          const int b = rowbase + lkg*4 + r;
          float v = 0.f;
          if (lrow < 10){
            const float y = h4[r] + x4[r] + b3[lrow];
            v = clamped ? 0.5f*(y + tin[b*10 + lrow]) : 0.5f*(uold4[r] + y);
            v = fminf(fmaxf(v, 0.f), 1.f);
          }
          uold4[r] = v;
          store_sys(uhlN + (size_t)b*ROWLEN + 1536 + lrow, packbf(v));
          store_sys(uhlN + (size_t)b*ROWLEN + 1552 + lrow, 0u);   // keep pads 0
          if (snap >= 0 && lrow < 10) dout[snap + 384000 + b*10 + lrow] = v;
        }
      }
      BARRIER(it);
    }
  } else {
    // ============================ u1 / u3 path =============================
    const bool IS3 = (tp >= 12);
    const int cbb  = IS3 ? (tp - 12) : (tp - 8);
    const int ct0  = cbb*8 + wv*2;
    s16x8 bh0[16], bl0[16], bh1[16], bl1[16];   // 256 VGPRs
    {
      const int base = IS3 ? B3A_OFF : B1_OFF;
      #pragma unroll
      for (int ks = 0; ks < 16; ++ks){
        const int ofA = base + ((ct0+0)*16 + ks)*512 + ln*8;
        const int ofB = base + ((ct0+1)*16 + ks)*512 + ln*8;
        bh0[ks] = *(const s16x8*)(Bh + ofA); bl0[ks] = *(const s16x8*)(Bl + ofA);
        bh1[ks] = *(const s16x8*)(Bh + ofB); bl1[ks] = *(const s16x8*)(Bl + ofB);
      }
    }
    s16x8 th0 = {0,0,0,0,0,0,0,0}, tl0 = th0, th1 = th0, tl1 = th0;  // u4 tail
    if (IS3){
      th0 = *(const s16x8*)(Bh + B3B_OFF + (ct0+0)*512 + ln*8);
      tl0 = *(const s16x8*)(Bl + B3B_OFF + (ct0+0)*512 + ln*8);
      th1 = *(const s16x8*)(Bh + B3B_OFF + (ct0+1)*512 + ln*8);
      tl1 = *(const s16x8*)(Bl + B3B_OFF + (ct0+1)*512 + ln*8);
    }
    const int colg0 = (IS3 ? 1024 : 0) + cbb*128 + wv*32;
    const int iA = (colg0 & 511) + lrow, iB = iA + 16;
    const float biasA = bias[colg0 + lrow], biasB = bias[colg0 + 16 + lrow];
    const float* uin = IS3 ? u3in : u1in;
    f32x4 uoldA, uoldB;
    #pragma unroll
    for (int r = 0; r < 4; ++r){
      const int b = rowbase + lkg*4 + r;
      uoldA[r] = (iA < 500) ? uin[b*500 + iA] : 0.f;
      uoldB[r] = (iB < 500) ? uin[b*500 + iB] : 0.f;
    }
    const int dseg = IS3 ? 256000 : 0;

    for (int it = 0; it < NITER; ++it){
      const uint* uhlB = uhl + (size_t)(it & 1)*ROWTOT;
      uint*       uhlN = uhl + (size_t)((it & 1) ^ 1)*ROWTOT;
      const int snap = (it == NFREE-1) ? 0 : ((it == NITER-1) ? 386560 : -1);
      { // ---- stage A = u2 (16 rows x 512) + u4 (16 rows x 32) ----
        const uint* sA = uhlB + (size_t)(rowbase + sg16)*ROWLEN + 512 + l16*4;
        u32x4 a0,a1,a2,a3,a4,a5,a6,a7, c0;
        SYSLD(a0, sA+0);   SYSLD(a1, sA+64);  SYSLD(a2, sA+128); SYSLD(a3, sA+192);
        SYSLD(a4, sA+256); SYSLD(a5, sA+320); SYSLD(a6, sA+384); SYSLD(a7, sA+448);
        const int row4 = tid >> 3, q = tid & 7;
        if (tid < 128)                           // waves 0-1 also stage u4 seg
          SYSLD(c0, uhlB + (size_t)(rowbase + row4)*ROWLEN + 1536 + q*4);
        WAITALL();
        const int ob = sg16*2048 + ((l16*8) ^ ((sg16 & 7) << 4));
        UNPK(a0, ob+0);   UNPK(a1, ob+128); UNPK(a2, ob+256); UNPK(a3, ob+384);
        UNPK(a4, ob+512); UNPK(a5, ob+640); UNPK(a6, ob+768); UNPK(a7, ob+896);
        if (tid < 128){
          // swizzle matches read side: (row4&7)<<4 (R2 used row4<<4 — rows
          // 8-15 landed outside the read window)
          const int ob4 = row4*2048 + ((1024 + q*8) ^ ((row4 & 7) << 4));
          UNPK(c0, ob4);
        }
      }
      __syncthreads();
      // ---- four independent chains: (hA,xA) for ct0, (hB,xB) for ct0+1 ----
      f32x4 hA = {0.f,0.f,0.f,0.f}, xA = {0.f,0.f,0.f,0.f};
      f32x4 hB = {0.f,0.f,0.f,0.f}, xB = {0.f,0.f,0.f,0.f};
      #pragma unroll
      for (int ks = 0; ks < 16; ++ks){
        const int off = abase ^ (ks*64);
        s16x8 aH = *(const s16x8*)(L + off);
        s16x8 aL = *(const s16x8*)(L + 32768 + off);
        hA = MFMA_BF16(aH, bh0[ks], hA, 0, 0, 0);
        xA = MFMA_BF16(aH, bl0[ks], xA, 0, 0, 0);
        xA = MFMA_BF16(aL, bh0[ks], xA, 0, 0, 0);
        hB = MFMA_BF16(aH, bh1[ks], hB, 0, 0, 0);
        xB = MFMA_BF16(aH, bl1[ks], xB, 0, 0, 0);
        xB = MFMA_BF16(aL, bh1[ks], xB, 0, 0, 0);
      }
      if (IS3){                                  // u4 tail kstep
        const int off = abase + 1024;
        s16x8 aH = *(const s16x8*)(L + off);
        s16x8 aL = *(const s16x8*)(L + 32768 + off);
        hA = MFMA_BF16(aH, th0, hA, 0, 0, 0);
        xA = MFMA_BF16(aH, tl0, xA, 0, 0, 0);
        xA = MFMA_BF16(aL, th0, xA, 0, 0, 0);
        hB = MFMA_BF16(aH, th1, hB, 0, 0, 0);
        xB = MFMA_BF16(aH, tl1, xB, 0, 0, 0);
        xB = MFMA_BF16(aL, th1, xB, 0, 0, 0);
      }
      // ---- epilogue: two 16x16 tiles ----
      #pragma unroll
      for (int r = 0; r < 4; ++r){
        const int b = rowbase + lkg*4 + r;
        {
          float y = hA[r] + xA[r] + biasA;
          if (!IS3) y += xw0p[b*512 + colg0 + lrow];
          float v = 0.5f*(uoldA[r] + y);
          v = fminf(fmaxf(v, 0.f), 1.f);
          if (iA >= 500) v = 0.f;
          uoldA[r] = v;
          store_sys(uhlN + (size_t)b*ROWLEN + colg0 + lrow, packbf(v));
          if (snap >= 0 && iA < 500) dout[snap + dseg + b*500 + iA] = v;
        }
        {
          float y = hB[r] + xB[r] + biasB;
          if (!IS3) y += xw0p[b*512 + colg0 + 16 + lrow];
          float v = 0.5f*(uoldB[r] + y);
          v = fminf(fmaxf(v, 0.f), 1.f);
          if (iB >= 500) v = 0.f;
          uoldB[r] = v;
          store_sys(uhlN + (size_t)b*ROWLEN + colg0 + 16 + lrow, packbf(v));
          if (snap >= 0 && iB < 500) dout[snap + dseg + b*500 + iB] = v;
        }
      }
      BARRIER(it);
    }
  }
}

// ------------------------------- launcher -----------------------------------
extern "C" void kernel_launch(void* const* d_in, const int* in_sizes, int n_in,
                              void* d_out, int out_size, void* d_ws, size_t ws_size,
                              hipStream_t stream)
{
  const float* x  = (const float*)d_in[0];
  const float* u1 = (const float*)d_in[1];
  const float* u2 = (const float*)d_in[2];
  const float* u3 = (const float*)d_in[3];
  const float* u4 = (const float*)d_in[4];
  const float* t  = (const float*)d_in[5];
  const float* W0 = (const float*)d_in[6];
  const float* W1 = (const float*)d_in[7];
  const float* W2 = (const float*)d_in[8];
  const float* W3 = (const float*)d_in[9];
  const float* b0 = (const float*)d_in[10];
  const float* b1 = (const float*)d_in[11];
  const float* b2 = (const float*)d_in[12];
  const float* b3 = (const float*)d_in[13];

  char* ws = (char*)d_ws;
  uint*  uhl  = (uint*) (ws + WS_UHL);
  float* xw0p = (float*)(ws + WS_XW0);
  float* bias = (float*)(ws + WS_BIAS);
  uint*  cnt  = (uint*) (ws + WS_CNT);
  short* Bh   = (short*)(ws + WS_BH);
  short* Bl   = (short*)(ws + WS_BL);
  float* dout = (float*)d_out;

  initK<<<256, 256, 0, stream>>>(u1, u2, u3, u4, b1, b2, uhl, bias, cnt);
  xw0K<<<256, 512, 0, stream>>>(x, W0, b0, xw0p);
  packK<<<2112, 64, 0, stream>>>(W1, W2, W3, Bh, Bl);

  void* args[] = { &Bh, &Bl, &uhl, &xw0p, &bias,
                   &u1, &u2, &u3, &u4, &t, &b3, &dout, &cnt };
  hipError_t e = hipLaunchCooperativeKernel((const void*)mainK, dim3(256),
                                            dim3(256), args, 0, stream);
  if (e != hipSuccess){
    mainK<<<256, 256, 0, stream>>>(Bh, Bl, uhl, xw0p, bias,
                                   u1, u2, u3, u4, t, b3, dout, cnt);
  }
  (void)in_sizes; (void)n_in; (void)out_size; (void)ws_size;
}